// Round 5
// baseline (726.609 us; speedup 1.0000x reference)
//
#include <hip/hip_runtime.h>
#include <hip/hip_bf16.h>
#include <stdint.h>

// Problem constants (fixed by the reference)
#define N_ 16384
#define M_ 4096
#define D_ 256
#define O_ 256

// Workspace layout (bytes) — stays under the ~20 MB proven in R4
#define WS_T    0          // float[N]        exp(sf+ba)       64 KB
#define WS_U    65536      // float[M]        exp(sc)          16 KB
#define WS_R    81920      // float[D]        colsum(Hc)        1 KB
#define WS_L    98304      // float[2*N]      partial denoms  128 KB
#define WS_WTP  229376     // ushort          Wt packed       128 KB
#define WS_BP   360448     // ushort          Hc packed         2 MB
#define WS_CP   2457600    // ushort[2*N*D]   partial C bf16   16 MB

typedef float  f32x4  __attribute__((ext_vector_type(4)));
typedef short  short8 __attribute__((ext_vector_type(8)));
typedef unsigned short ushortx4 __attribute__((ext_vector_type(4)));

// fp32 -> bf16 (RNE). Inputs are finite so no NaN handling.
__device__ __forceinline__ unsigned short f2bf(float f) {
  uint32_t u = __float_as_uint(f);
  u += 0x7FFFu + ((u >> 16) & 1u);
  return (unsigned short)(u >> 16);
}
// packed pair fp32 -> bf16 (compiler can emit v_cvt_pk_bf16_f32)
__device__ __forceinline__ uint32_t cvtpk(float a, float b) {
  __hip_bfloat162 h = __float22bfloat162_rn(float2{a, b});
  uint32_t u;
  __builtin_memcpy(&u, &h, 4);
  return u;
}
__device__ __forceinline__ float bf2f(unsigned short v) {
  return __uint_as_float((uint32_t)v << 16);
}

// ---------------------------------------------------------------------------
// Prep 1: per-row dot with weight vector, then exp(dot + bias).
__global__ __launch_bounds__(256) void rowdot_exp_kernel(
    const float* __restrict__ X, const float* __restrict__ w,
    const float* __restrict__ bias, float* __restrict__ outv) {
  int wv = threadIdx.x >> 6, lane = threadIdx.x & 63;
  int row = blockIdx.x * 4 + wv;
  const float4* x4 = (const float4*)(X + (size_t)row * D_);
  const float4* w4 = (const float4*)w;
  float4 xa = x4[lane], wa4 = w4[lane];
  float s = xa.x * wa4.x + xa.y * wa4.y + xa.z * wa4.z + xa.w * wa4.w;
#pragma unroll
  for (int off = 32; off > 0; off >>= 1) s += __shfl_xor(s, off);
  if (lane == 0) outv[row] = expf(s + (bias ? bias[0] : 0.0f));
}

// ---------------------------------------------------------------------------
// Prep 2: Hc [M,D] fp32 -> BP fragment-major bf16 (k-PERMUTED) + R = colsum(Hc).
// Fragment k-order per lane(q,m): j<4 -> k = q*4+j ; j>=4 -> k = 16+q*4+(j-4).
// This matches the main kernel's line-tiling adj loads; permutation applied to
// both A and B leaves the contraction result unchanged.
__global__ __launch_bounds__(256) void hc_pack_kernel(
    const float* __restrict__ Hc, unsigned short* __restrict__ BP,
    float* __restrict__ R) {
  __shared__ float tile[64][65];
  __shared__ float red[4][64];
  int bk = blockIdx.x >> 2;   // 64 tiles along M (k)
  int bc = blockIdx.x & 3;    // 4 tiles along D (col)
  int k0 = bk * 64, col0 = bc * 64;
  int t = threadIdx.x;
  int lane = t & 63, wv = t >> 6;
  int m = lane & 15, q = lane >> 4;
  float colsum = 0.0f;
#pragma unroll
  for (int i = 0; i < 16; ++i) {
    int e = t + 256 * i;
    int kk = e >> 6, cc = e & 63;
    float v = Hc[(size_t)(k0 + kk) * D_ + col0 + cc];
    tile[kk][cc] = v;
    colsum += v;
  }
  red[wv][t & 63] = colsum;
  __syncthreads();
  if (t < 64)
    atomicAdd(&R[col0 + t], red[0][t] + red[1][t] + red[2][t] + red[3][t]);
#pragma unroll
  for (int t8 = 0; t8 < 2; ++t8) {
    int tile_id = t8 * 4 + wv;
    int sub = tile_id >> 2, g = tile_id & 3;
    int kgg = bk * 2 + sub;
    int cgg = bc * 4 + g;
    short8 v8;
#pragma unroll
    for (int j = 0; j < 8; ++j) {
      int kloc = ((j >> 2) << 4) + q * 4 + (j & 3);  // permuted k within 32
      v8[j] = (short)f2bf(tile[sub * 32 + kloc][g * 16 + m]);
    }
    *(short8*)(BP + ((size_t)(kgg * 16 + cgg) * 64 + lane) * 8) = v8;
  }
}

// ---------------------------------------------------------------------------
// Prep 3: Wt [O,D] fp32 -> WtP fragment-major bf16 (NON-permuted; used only by
// the epilogue GEMM whose A side is also non-permuted).
__global__ __launch_bounds__(256) void wt_pack_kernel(
    const float* __restrict__ Wt, unsigned short* __restrict__ WtP) {
  int t = blockIdx.x * 256 + threadIdx.x;    // 0..8191
  int lane = t & 63, cg = (t >> 6) & 15, kg = t >> 10;
  int m = lane & 15, q = lane >> 4;
  const float* src = Wt + (size_t)(cg * 16 + m) * D_ + kg * 32 + q * 8;
  float4 w0 = *(const float4*)src, w1 = *(const float4*)(src + 4);
  short8 v8;
  v8[0] = (short)f2bf(w0.x); v8[1] = (short)f2bf(w0.y);
  v8[2] = (short)f2bf(w0.z); v8[3] = (short)f2bf(w0.w);
  v8[4] = (short)f2bf(w1.x); v8[5] = (short)f2bf(w1.y);
  v8[6] = (short)f2bf(w1.z); v8[7] = (short)f2bf(w1.w);
  *(short8*)(WtP + (size_t)t * 8) = v8;
}

// ---------------------------------------------------------------------------
// transform 8 adj values (2 permuted float4s) -> bf16 A'-fragment + row-sum
__device__ __forceinline__ short8 transform8(float4 A0, float4 A1, float t,
                                             float4 u0, float4 u1, float& rs) {
  float p0 = fmaf(A0.x, t * u0.x, -A0.x);
  float p1 = fmaf(A0.y, t * u0.y, -A0.y);
  float p2 = fmaf(A0.z, t * u0.z, -A0.z);
  float p3 = fmaf(A0.w, t * u0.w, -A0.w);
  float p4 = fmaf(A1.x, t * u1.x, -A1.x);
  float p5 = fmaf(A1.y, t * u1.y, -A1.y);
  float p6 = fmaf(A1.z, t * u1.z, -A1.z);
  float p7 = fmaf(A1.w, t * u1.w, -A1.w);
  rs += ((p0 + p1) + (p2 + p3)) + ((p4 + p5) + (p6 + p7));
  union { short8 s; uint32_t u[4]; } r;
  r.u[0] = cvtpk(p0, p1);
  r.u[1] = cvtpk(p2, p3);
  r.u[2] = cvtpk(p4, p5);
  r.u[3] = cvtpk(p6, p7);
  return r.s;
}

// ---------------------------------------------------------------------------
// Main split-K kernel (barrier-free K loop, row-stacked waves):
//   block = 128 rows x 64 cols x K-half 2048; wave w owns rows w*32..w*32+31
//   (adj-private per wave: no cross-wave adj duplication). A' fragments built
//   in registers with k-permuted mapping so each adj float4 load tiles cache
//   lines exactly once. B fragments from k-permuted prepacked BP (L1/L2-hot).
//   Partial C -> bf16 plain stores; partial denom -> plain stores (cg==0).
// Grid = 128 rg x 4 cg x 2 kh = 1024 blocks x 256 thr -> 4 blocks/CU.
__global__ __launch_bounds__(256, 4) void main_kernel(
    const float* __restrict__ adj, const unsigned short* __restrict__ BP,
    const float* __restrict__ tv, const float* __restrict__ uv,
    unsigned short* __restrict__ Cp, float* __restrict__ Lp) {
  __shared__ float u_lds[2048];
  int tid = threadIdx.x;
  int w = tid >> 6, lane = tid & 63;
  int q = lane >> 4, m = lane & 15;
  int bid = blockIdx.x;
  int kh = bid & 1, cg = (bid >> 1) & 3, rg = bid >> 3;
  int r0 = rg * 128 + w * 32;
  int c0 = cg * 64;

  for (int i = tid; i < 2048; i += 256) u_lds[i] = uv[kh * 2048 + i];

  float t0 = tv[r0 + m], t1 = tv[r0 + 16 + m];
  const float* a0 = adj + (size_t)(r0 + m) * M_ + kh * 2048 + q * 4;
  const float* a1 = a0 + (size_t)16 * M_;
  const unsigned short* bb =
      BP + ((size_t)(kh * 64) * 16 + cg * 4) * 512 + (size_t)lane * 8;

  f32x4 acc[2][4];
#pragma unroll
  for (int s = 0; s < 2; ++s)
#pragma unroll
    for (int n = 0; n < 4; ++n) acc[s][n] = (f32x4){0.f, 0.f, 0.f, 0.f};
  float rs0 = 0.0f, rs1 = 0.0f;

  __syncthreads();  // u_lds ready (only barrier in the kernel)

  // adj register double-buffer: set X = even ksteps, set Y = odd ksteps
  float4 xA0 = *(const float4*)(a0);      // rows s0, k part {q*4..+3}
  float4 xA1 = *(const float4*)(a0 + 16); // rows s0, k part {16+q*4..+3}
  float4 xB0 = *(const float4*)(a1);
  float4 xB1 = *(const float4*)(a1 + 16);
  float4 yA0 = *(const float4*)(a0 + 32);
  float4 yA1 = *(const float4*)(a0 + 48);
  float4 yB0 = *(const float4*)(a1 + 32);
  float4 yB1 = *(const float4*)(a1 + 48);

  for (int kk = 0; kk < 64; kk += 2) {
    // ---- kstep kk (set X)
    {
      const unsigned short* bp = bb + (size_t)kk * 8192;
      short8 b0 = *(const short8*)(bp);
      short8 b1 = *(const short8*)(bp + 512);
      short8 b2 = *(const short8*)(bp + 1024);
      short8 b3 = *(const short8*)(bp + 1536);
      float4 u0 = *(const float4*)&u_lds[kk * 32 + q * 4];
      float4 u1 = *(const float4*)&u_lds[kk * 32 + 16 + q * 4];
      short8 af0 = transform8(xA0, xA1, t0, u0, u1, rs0);
      short8 af1 = transform8(xB0, xB1, t1, u0, u1, rs1);
      int k2 = ((kk + 2) & 63) * 32;  // wrap: harmless reload of kstep 0
      xA0 = *(const float4*)(a0 + k2);
      xA1 = *(const float4*)(a0 + k2 + 16);
      xB0 = *(const float4*)(a1 + k2);
      xB1 = *(const float4*)(a1 + k2 + 16);
      acc[0][0] = __builtin_amdgcn_mfma_f32_16x16x32_bf16(af0, b0, acc[0][0], 0, 0, 0);
      acc[0][1] = __builtin_amdgcn_mfma_f32_16x16x32_bf16(af0, b1, acc[0][1], 0, 0, 0);
      acc[0][2] = __builtin_amdgcn_mfma_f32_16x16x32_bf16(af0, b2, acc[0][2], 0, 0, 0);
      acc[0][3] = __builtin_amdgcn_mfma_f32_16x16x32_bf16(af0, b3, acc[0][3], 0, 0, 0);
      acc[1][0] = __builtin_amdgcn_mfma_f32_16x16x32_bf16(af1, b0, acc[1][0], 0, 0, 0);
      acc[1][1] = __builtin_amdgcn_mfma_f32_16x16x32_bf16(af1, b1, acc[1][1], 0, 0, 0);
      acc[1][2] = __builtin_amdgcn_mfma_f32_16x16x32_bf16(af1, b2, acc[1][2], 0, 0, 0);
      acc[1][3] = __builtin_amdgcn_mfma_f32_16x16x32_bf16(af1, b3, acc[1][3], 0, 0, 0);
    }
    // ---- kstep kk+1 (set Y)
    {
      const unsigned short* bp = bb + (size_t)(kk + 1) * 8192;
      short8 b0 = *(const short8*)(bp);
      short8 b1 = *(const short8*)(bp + 512);
      short8 b2 = *(const short8*)(bp + 1024);
      short8 b3 = *(const short8*)(bp + 1536);
      float4 u0 = *(const float4*)&u_lds[(kk + 1) * 32 + q * 4];
      float4 u1 = *(const float4*)&u_lds[(kk + 1) * 32 + 16 + q * 4];
      short8 af0 = transform8(yA0, yA1, t0, u0, u1, rs0);
      short8 af1 = transform8(yB0, yB1, t1, u0, u1, rs1);
      int k3 = ((kk + 3) & 63) * 32;
      yA0 = *(const float4*)(a0 + k3);
      yA1 = *(const float4*)(a0 + k3 + 16);
      yB0 = *(const float4*)(a1 + k3);
      yB1 = *(const float4*)(a1 + k3 + 16);
      acc[0][0] = __builtin_amdgcn_mfma_f32_16x16x32_bf16(af0, b0, acc[0][0], 0, 0, 0);
      acc[0][1] = __builtin_amdgcn_mfma_f32_16x16x32_bf16(af0, b1, acc[0][1], 0, 0, 0);
      acc[0][2] = __builtin_amdgcn_mfma_f32_16x16x32_bf16(af0, b2, acc[0][2], 0, 0, 0);
      acc[0][3] = __builtin_amdgcn_mfma_f32_16x16x32_bf16(af0, b3, acc[0][3], 0, 0, 0);
      acc[1][0] = __builtin_amdgcn_mfma_f32_16x16x32_bf16(af1, b0, acc[1][0], 0, 0, 0);
      acc[1][1] = __builtin_amdgcn_mfma_f32_16x16x32_bf16(af1, b1, acc[1][1], 0, 0, 0);
      acc[1][2] = __builtin_amdgcn_mfma_f32_16x16x32_bf16(af1, b2, acc[1][2], 0, 0, 0);
      acc[1][3] = __builtin_amdgcn_mfma_f32_16x16x32_bf16(af1, b3, acc[1][3], 0, 0, 0);
    }
  }

  // partial softmax denominators (only cg==0 blocks store; others redundant)
  rs0 += __shfl_xor(rs0, 16); rs0 += __shfl_xor(rs0, 32);
  rs1 += __shfl_xor(rs1, 16); rs1 += __shfl_xor(rs1, 32);
  if (cg == 0 && lane < 16) {
    Lp[(size_t)kh * N_ + r0 + m] = rs0;
    Lp[(size_t)kh * N_ + r0 + 16 + m] = rs1;
  }

  // partial C -> bf16 plain stores (each element written exactly once per kh)
#pragma unroll
  for (int s = 0; s < 2; ++s)
#pragma unroll
    for (int n = 0; n < 4; ++n) {
      int col = c0 + n * 16 + m;
#pragma unroll
      for (int r = 0; r < 4; ++r) {
        size_t row = (size_t)r0 + s * 16 + q * 4 + r;  // C/D: row=(lane>>4)*4+reg
        Cp[((size_t)kh * N_ + row) * D_ + col] = f2bf(acc[s][n][r]);
      }
    }
}

// ---------------------------------------------------------------------------
// Epilogue: attn = (Cp0+Cp1 + R)/(L0+L1+M) + Hf -> LDS bf16 -> relu(attn@Wt^T+bt)
__global__ __launch_bounds__(256, 4) void epilogue_kernel(
    const unsigned short* __restrict__ Cp, const float* __restrict__ Lp,
    const float* __restrict__ Rv, const float* __restrict__ Hf,
    const unsigned short* __restrict__ WtP, const float* __restrict__ bt,
    float* __restrict__ out) {
  __shared__ alignas(16) unsigned short attn[32][264];  // +8 pad
  int tid = threadIdx.x;
  int w = tid >> 6, lane = tid & 63;
  int rtile = w & 1, chalf = w >> 1;
  int q = lane >> 4, m = lane & 15;
  int i0 = blockIdx.x * 32;

  float4 rv = *(const float4*)(Rv + lane * 4);
#pragma unroll
  for (int rr = 0; rr < 8; ++rr) {
    int r = w * 8 + rr;                       // wave w owns rows w*8..w*8+7
    size_t row = (size_t)i0 + r;
    float invL = 1.0f / (Lp[row] + Lp[N_ + row] + (float)M_);
    ushortx4 cA = *(const ushortx4*)(Cp + row * D_ + lane * 4);
    ushortx4 cB = *(const ushortx4*)(Cp + ((size_t)N_ + row) * D_ + lane * 4);
    float4 hv = *(const float4*)(Hf + row * D_ + lane * 4);
    attn[r][lane * 4 + 0] = f2bf(fmaf(bf2f(cA[0]) + bf2f(cB[0]) + rv.x, invL, hv.x));
    attn[r][lane * 4 + 1] = f2bf(fmaf(bf2f(cA[1]) + bf2f(cB[1]) + rv.y, invL, hv.y));
    attn[r][lane * 4 + 2] = f2bf(fmaf(bf2f(cA[2]) + bf2f(cB[2]) + rv.z, invL, hv.z));
    attn[r][lane * 4 + 3] = f2bf(fmaf(bf2f(cA[3]) + bf2f(cB[3]) + rv.w, invL, hv.w));
  }
  __syncthreads();

  f32x4 facc[8];
#pragma unroll
  for (int n = 0; n < 8; ++n) facc[n] = (f32x4){0.f, 0.f, 0.f, 0.f};
  const unsigned short* wwave = WtP + (size_t)chalf * 4096 + (size_t)lane * 8;
#pragma unroll
  for (int kf = 0; kf < 8; ++kf) {
    short8 af = *(const short8*)&attn[rtile * 16 + m][kf * 32 + q * 8];
#pragma unroll
    for (int n = 0; n < 8; ++n) {
      short8 bf = *(const short8*)(wwave + ((size_t)kf * 16 + n) * 512);
      facc[n] = __builtin_amdgcn_mfma_f32_16x16x32_bf16(af, bf, facc[n], 0, 0, 0);
    }
  }
#pragma unroll
  for (int n = 0; n < 8; ++n) {
    int col = chalf * 128 + n * 16 + m;
    float b = bt[col];
#pragma unroll
    for (int r = 0; r < 4; ++r) {
      size_t row = (size_t)i0 + rtile * 16 + q * 4 + r;
      out[row * O_ + col] = fmaxf(facc[n][r] + b, 0.0f);
    }
  }
}

// ---------------------------------------------------------------------------
extern "C" void kernel_launch(void* const* d_in, const int* in_sizes, int n_in,
                              void* d_out, int out_size, void* d_ws, size_t ws_size,
                              hipStream_t stream) {
  const float* Hf  = (const float*)d_in[0];  // [N,D]
  const float* Hc  = (const float*)d_in[1];  // [M,D]
  const float* adj = (const float*)d_in[2];  // [N,M]
  const float* wa  = (const float*)d_in[3];  // [2D]
  const float* ba  = (const float*)d_in[4];  // [1]
  const float* Wt  = (const float*)d_in[5];  // [O,D]
  const float* bt  = (const float*)d_in[6];  // [O]
  float* out = (float*)d_out;

  char* ws = (char*)d_ws;
  float* tv = (float*)(ws + WS_T);
  float* uv = (float*)(ws + WS_U);
  float* Rv = (float*)(ws + WS_R);
  float* Lp = (float*)(ws + WS_L);
  unsigned short* WtP = (unsigned short*)(ws + WS_WTP);
  unsigned short* BP  = (unsigned short*)(ws + WS_BP);
  unsigned short* Cp  = (unsigned short*)(ws + WS_CP);

  hipMemsetAsync(Rv, 0, D_ * sizeof(float), stream);  // atomic target

  rowdot_exp_kernel<<<N_ / 4, 256, 0, stream>>>(Hf, wa, ba, tv);           // t = exp(sf+ba)
  rowdot_exp_kernel<<<M_ / 4, 256, 0, stream>>>(Hc, wa + D_, nullptr, uv); // u = exp(sc)
  hc_pack_kernel<<<256, 256, 0, stream>>>(Hc, BP, Rv);
  wt_pack_kernel<<<32, 256, 0, stream>>>(Wt, WtP);

  main_kernel<<<1024, 256, 0, stream>>>(adj, BP, tv, uv, Cp, Lp);
  epilogue_kernel<<<N_ / 32, 256, 0, stream>>>(Cp, Lp, Rv, Hf, WtP, bt, out);
}

// Round 6
// 513.930 us; speedup vs baseline: 1.4138x; 1.4138x over previous
//
#include <hip/hip_runtime.h>
#include <hip/hip_bf16.h>
#include <stdint.h>

// Problem constants (fixed by the reference)
#define N_ 16384
#define M_ 4096
#define D_ 256
#define O_ 256

// Workspace layout (bytes). Total ~149 MB — assumes ws_size covers it.
#define WS_T    0          // float[N]        exp(sf+ba)       64 KB
#define WS_U    65536      // float[M]        exp(sc)          16 KB
#define WS_R    81920      // float[D]        colsum(Hc)        1 KB
#define WS_LSUM 98304      // float[N]        row denoms       64 KB
#define WS_WTP  163840     // ushort          Wt packed       128 KB
#define WS_BP   360448     // ushort          Hc packed         2 MB
#define WS_CP   2457600    // ushort[2*N*D]   partial C bf16   16 MB
#define WS_AP   20971520   // ushort[N*M]     A' fragments    128 MB

typedef float  f32x4  __attribute__((ext_vector_type(4)));
typedef short  short8 __attribute__((ext_vector_type(8)));
typedef unsigned short ushortx4 __attribute__((ext_vector_type(4)));

// fp32 -> bf16 (RNE). Inputs are finite so no NaN handling.
__device__ __forceinline__ unsigned short f2bf(float f) {
  uint32_t u = __float_as_uint(f);
  u += 0x7FFFu + ((u >> 16) & 1u);
  return (unsigned short)(u >> 16);
}
// packed pair fp32 -> bf16
__device__ __forceinline__ uint32_t cvtpk(float a, float b) {
  __hip_bfloat162 h = __float22bfloat162_rn(float2{a, b});
  uint32_t u;
  __builtin_memcpy(&u, &h, 4);
  return u;
}
__device__ __forceinline__ float bf2f(unsigned short v) {
  return __uint_as_float((uint32_t)v << 16);
}

// ---------------------------------------------------------------------------
// Prep 1: per-row dot with weight vector, then exp(dot + bias).
__global__ __launch_bounds__(256) void rowdot_exp_kernel(
    const float* __restrict__ X, const float* __restrict__ w,
    const float* __restrict__ bias, float* __restrict__ outv) {
  int wv = threadIdx.x >> 6, lane = threadIdx.x & 63;
  int row = blockIdx.x * 4 + wv;
  const float4* x4 = (const float4*)(X + (size_t)row * D_);
  const float4* w4 = (const float4*)w;
  float4 xa = x4[lane], wa4 = w4[lane];
  float s = xa.x * wa4.x + xa.y * wa4.y + xa.z * wa4.z + xa.w * wa4.w;
#pragma unroll
  for (int off = 32; off > 0; off >>= 1) s += __shfl_xor(s, off);
  if (lane == 0) outv[row] = expf(s + (bias ? bias[0] : 0.0f));
}

// ---------------------------------------------------------------------------
// Prep 2: Hc [M,D] fp32 -> BP fragment-major bf16 (standard k-order) + colsum.
// BP[((kg*16 + cg)*64 + lane)*8 + j] = bf16(Hc[kg*32+q*8+j][cg*16+m]), lane=q*16+m.
__global__ __launch_bounds__(256) void hc_pack_kernel(
    const float* __restrict__ Hc, unsigned short* __restrict__ BP,
    float* __restrict__ R) {
  __shared__ float tile[64][65];
  __shared__ float red[4][64];
  int bk = blockIdx.x >> 2;   // 64 tiles along M (k)
  int bc = blockIdx.x & 3;    // 4 tiles along D (col)
  int k0 = bk * 64, col0 = bc * 64;
  int t = threadIdx.x;
  int lane = t & 63, wv = t >> 6;
  int m = lane & 15, q = lane >> 4;
  float colsum = 0.0f;
#pragma unroll
  for (int i = 0; i < 16; ++i) {
    int e = t + 256 * i;
    int kk = e >> 6, cc = e & 63;
    float v = Hc[(size_t)(k0 + kk) * D_ + col0 + cc];
    tile[kk][cc] = v;
    colsum += v;
  }
  red[wv][t & 63] = colsum;
  __syncthreads();
  if (t < 64)
    atomicAdd(&R[col0 + t], red[0][t] + red[1][t] + red[2][t] + red[3][t]);
#pragma unroll
  for (int t8 = 0; t8 < 2; ++t8) {
    int tile_id = t8 * 4 + wv;
    int sub = tile_id >> 2, g = tile_id & 3;
    int kgg = bk * 2 + sub;
    int cgg = bc * 4 + g;
    short8 v8;
#pragma unroll
    for (int j = 0; j < 8; ++j)
      v8[j] = (short)f2bf(tile[sub * 32 + q * 8 + j][g * 16 + m]);
    *(short8*)(BP + ((size_t)(kgg * 16 + cgg) * 64 + lane) * 8) = v8;
  }
}

// ---------------------------------------------------------------------------
// Prep 3: Wt [O,D] fp32 -> WtP fragment-major bf16 (kg 0..7, cg 0..15).
__global__ __launch_bounds__(256) void wt_pack_kernel(
    const float* __restrict__ Wt, unsigned short* __restrict__ WtP) {
  int t = blockIdx.x * 256 + threadIdx.x;    // 0..8191
  int lane = t & 63, cg = (t >> 6) & 15, kg = t >> 10;
  int m = lane & 15, q = lane >> 4;
  const float* src = Wt + (size_t)(cg * 16 + m) * D_ + kg * 32 + q * 8;
  float4 w0 = *(const float4*)src, w1 = *(const float4*)(src + 4);
  short8 v8;
  v8[0] = (short)f2bf(w0.x); v8[1] = (short)f2bf(w0.y);
  v8[2] = (short)f2bf(w0.z); v8[3] = (short)f2bf(w0.w);
  v8[4] = (short)f2bf(w1.x); v8[5] = (short)f2bf(w1.y);
  v8[6] = (short)f2bf(w1.z); v8[7] = (short)f2bf(w1.w);
  *(short8*)(WtP + (size_t)t * 8) = v8;
}

// ---------------------------------------------------------------------------
// transform 8 adj values -> bf16 A'-fragment (slots j: k = q*8+j) + row-sum
__device__ __forceinline__ short8 transform8(float4 A0, float4 A1, float t,
                                             float4 u0, float4 u1, float& rs) {
  float p0 = fmaf(A0.x, t * u0.x, -A0.x);
  float p1 = fmaf(A0.y, t * u0.y, -A0.y);
  float p2 = fmaf(A0.z, t * u0.z, -A0.z);
  float p3 = fmaf(A0.w, t * u0.w, -A0.w);
  float p4 = fmaf(A1.x, t * u1.x, -A1.x);
  float p5 = fmaf(A1.y, t * u1.y, -A1.y);
  float p6 = fmaf(A1.z, t * u1.z, -A1.z);
  float p7 = fmaf(A1.w, t * u1.w, -A1.w);
  rs += ((p0 + p1) + (p2 + p3)) + ((p4 + p5) + (p6 + p7));
  union { short8 s; uint32_t u[4]; } r;
  r.u[0] = cvtpk(p0, p1);
  r.u[1] = cvtpk(p2, p3);
  r.u[2] = cvtpk(p4, p5);
  r.u[3] = cvtpk(p6, p7);
  return r.s;
}

// ---------------------------------------------------------------------------
// Transform kernel (pure streaming, HBM-bound):
//   reads adj rows r0..r0+15 (block b = r0/16), writes A' bf16 MFMA A-fragments
//   AP[((b*128 + kg)*64 + lane)*8 + j] = A'[b*16+m][kg*32+q*8+j], lane=q*16+m.
//   Exact row-sums reduced in-block (block owns full rows) -> Lsum, no atomics.
// Grid = N/16 = 1024 blocks x 256 thr -> 4 blocks/CU. Wave w handles
// kg = w, w+4, ..., 124 (32 iters); depth-2 register prefetch on adj.
__global__ __launch_bounds__(256, 4) void transform_kernel(
    const float* __restrict__ adj, const float* __restrict__ tv,
    const float* __restrict__ uv, unsigned short* __restrict__ AP,
    float* __restrict__ Lsum) {
  __shared__ float u_lds[M_];     // 16 KB
  __shared__ float red[4][16];
  int tid = threadIdx.x;
  int w = tid >> 6, lane = tid & 63;
  int q = lane >> 4, m = lane & 15;
  int b = blockIdx.x;
  int r0 = b * 16;

  for (int i = tid; i < M_; i += 256) u_lds[i] = uv[i];

  float t_r = tv[r0 + m];
  const float* arow = adj + (size_t)(r0 + m) * M_ + q * 8;
  unsigned short* apb = AP + (size_t)b * 128 * 512 + (size_t)lane * 8;
  float rs = 0.0f;
  __syncthreads();  // u_lds ready

  // depth-2 prefetch: sets P (even i) and Q (odd i)
  float4 pA0 = *(const float4*)(arow + (size_t)w * 32);
  float4 pA1 = *(const float4*)(arow + (size_t)w * 32 + 4);
  float4 qA0 = *(const float4*)(arow + (size_t)(w + 4) * 32);
  float4 qA1 = *(const float4*)(arow + (size_t)(w + 4) * 32 + 4);

  for (int i = 0; i < 32; i += 2) {
    int kg0 = w + 4 * i;
    int kg1 = w + 4 * (i + 1);
    int kg2 = (i + 2 < 32) ? w + 4 * (i + 2) : w;   // wrap: harmless reload
    float4 nA0 = *(const float4*)(arow + (size_t)kg2 * 32);
    float4 nA1 = *(const float4*)(arow + (size_t)kg2 * 32 + 4);
    {
      float4 u0 = *(const float4*)&u_lds[kg0 * 32 + q * 8];
      float4 u1 = *(const float4*)&u_lds[kg0 * 32 + q * 8 + 4];
      short8 af = transform8(pA0, pA1, t_r, u0, u1, rs);
      *(short8*)(apb + (size_t)kg0 * 512) = af;
    }
    int kg3 = (i + 3 < 32) ? w + 4 * (i + 3) : w;
    float4 oA0 = *(const float4*)(arow + (size_t)kg3 * 32);
    float4 oA1 = *(const float4*)(arow + (size_t)kg3 * 32 + 4);
    {
      float4 u0 = *(const float4*)&u_lds[kg1 * 32 + q * 8];
      float4 u1 = *(const float4*)&u_lds[kg1 * 32 + q * 8 + 4];
      short8 af = transform8(qA0, qA1, t_r, u0, u1, rs);
      *(short8*)(apb + (size_t)kg1 * 512) = af;
    }
    pA0 = nA0; pA1 = nA1; qA0 = oA0; qA1 = oA1;
  }

  // row-sums: reduce across the 4 k-quads (lanes m, m+16, m+32, m+48)
  rs += __shfl_xor(rs, 16);
  rs += __shfl_xor(rs, 32);
  if (lane < 16) red[w][lane] = rs;
  __syncthreads();
  if (tid < 16)
    Lsum[r0 + tid] = red[0][tid] + red[1][tid] + red[2][tid] + red[3][tid];
}

// ---------------------------------------------------------------------------
// Main pure-GEMM kernel (barrier-free, all loads prepacked-contiguous):
//   C_partial = A'(kh half) @ Hc ; A' fragments from AP (HBM stream, read once),
//   B fragments from BP (L2-resident, 2 MB). Block = 32 rows x 256 cols,
//   4 waves split cols; split-K=2 across blocks. Cp bf16 plain stores.
// Grid = 1024 x 256 thr -> 4 blocks/CU = 16 waves/CU. Depth-1 double-set
// register prefetch (X/Y), no barriers, no LDS.
__global__ __launch_bounds__(256, 4) void main_kernel(
    const unsigned short* __restrict__ AP, const unsigned short* __restrict__ BP,
    unsigned short* __restrict__ Cp) {
  int tid = threadIdx.x;
  int w = tid >> 6, lane = tid & 63;
  int q = lane >> 4, m = lane & 15;
  int bid = blockIdx.x;
  int kh = bid & 1, rb = bid >> 1;
  int r16 = rb * 2;                 // two 16-row A tiles
  int c0 = w * 64;

  const unsigned short* a0 =
      AP + ((size_t)r16 * 128 + kh * 64) * 512 + (size_t)lane * 8;
  const unsigned short* a1 = a0 + (size_t)128 * 512;
  const unsigned short* bb =
      BP + ((size_t)(kh * 64) * 16 + w * 4) * 512 + (size_t)lane * 8;

  f32x4 acc[2][4];
#pragma unroll
  for (int s = 0; s < 2; ++s)
#pragma unroll
    for (int n = 0; n < 4; ++n) acc[s][n] = (f32x4){0.f, 0.f, 0.f, 0.f};

  // X = even ksteps, Y = odd ksteps
  short8 aX0 = *(const short8*)(a0);
  short8 aX1 = *(const short8*)(a1);
  short8 aY0 = *(const short8*)(a0 + 512);
  short8 aY1 = *(const short8*)(a1 + 512);
  short8 bX[4], bY[4];
#pragma unroll
  for (int n = 0; n < 4; ++n) bX[n] = *(const short8*)(bb + n * 512);
#pragma unroll
  for (int n = 0; n < 4; ++n) bY[n] = *(const short8*)(bb + 8192 + n * 512);

  for (int kk = 0; kk < 64; kk += 2) {
    // consume kstep kk (X), prefetch kk+2 into X
    {
      int k2 = (kk + 2) & 63;      // wrap: harmless reload of kstep 0
      short8 nA0 = *(const short8*)(a0 + (size_t)k2 * 512);
      short8 nA1 = *(const short8*)(a1 + (size_t)k2 * 512);
      short8 nB[4];
#pragma unroll
      for (int n = 0; n < 4; ++n)
        nB[n] = *(const short8*)(bb + (size_t)k2 * 8192 + n * 512);
#pragma unroll
      for (int n = 0; n < 4; ++n) {
        acc[0][n] = __builtin_amdgcn_mfma_f32_16x16x32_bf16(aX0, bX[n], acc[0][n], 0, 0, 0);
        acc[1][n] = __builtin_amdgcn_mfma_f32_16x16x32_bf16(aX1, bX[n], acc[1][n], 0, 0, 0);
      }
      aX0 = nA0; aX1 = nA1;
#pragma unroll
      for (int n = 0; n < 4; ++n) bX[n] = nB[n];
    }
    // consume kstep kk+1 (Y), prefetch kk+3 into Y
    {
      int k3 = (kk + 3) & 63;
      short8 nA0 = *(const short8*)(a0 + (size_t)k3 * 512);
      short8 nA1 = *(const short8*)(a1 + (size_t)k3 * 512);
      short8 nB[4];
#pragma unroll
      for (int n = 0; n < 4; ++n)
        nB[n] = *(const short8*)(bb + (size_t)k3 * 8192 + n * 512);
#pragma unroll
      for (int n = 0; n < 4; ++n) {
        acc[0][n] = __builtin_amdgcn_mfma_f32_16x16x32_bf16(aY0, bY[n], acc[0][n], 0, 0, 0);
        acc[1][n] = __builtin_amdgcn_mfma_f32_16x16x32_bf16(aY1, bY[n], acc[1][n], 0, 0, 0);
      }
      aY0 = nA0; aY1 = nA1;
#pragma unroll
      for (int n = 0; n < 4; ++n) bY[n] = nB[n];
    }
  }

  // partial C -> bf16 plain stores
#pragma unroll
  for (int s = 0; s < 2; ++s)
#pragma unroll
    for (int n = 0; n < 4; ++n) {
      int col = c0 + n * 16 + m;
#pragma unroll
      for (int r = 0; r < 4; ++r) {
        size_t row = (size_t)rb * 32 + s * 16 + q * 4 + r;  // C/D: row=(lane>>4)*4+reg
        Cp[((size_t)kh * N_ + row) * D_ + col] = f2bf(acc[s][n][r]);
      }
    }
}

// ---------------------------------------------------------------------------
// Epilogue: attn = (Cp0+Cp1 + R)/(Lsum + M) + Hf -> LDS bf16 -> relu(attn@Wt^T+bt)
__global__ __launch_bounds__(256, 4) void epilogue_kernel(
    const unsigned short* __restrict__ Cp, const float* __restrict__ Lsum,
    const float* __restrict__ Rv, const float* __restrict__ Hf,
    const unsigned short* __restrict__ WtP, const float* __restrict__ bt,
    float* __restrict__ out) {
  __shared__ alignas(16) unsigned short attn[32][264];  // +8 pad
  int tid = threadIdx.x;
  int w = tid >> 6, lane = tid & 63;
  int rtile = w & 1, chalf = w >> 1;
  int q = lane >> 4, m = lane & 15;
  int i0 = blockIdx.x * 32;

  float4 rv = *(const float4*)(Rv + lane * 4);
#pragma unroll
  for (int rr = 0; rr < 8; ++rr) {
    int r = w * 8 + rr;                       // wave w owns rows w*8..w*8+7
    size_t row = (size_t)i0 + r;
    float invL = 1.0f / (Lsum[row] + (float)M_);
    ushortx4 cA = *(const ushortx4*)(Cp + row * D_ + lane * 4);
    ushortx4 cB = *(const ushortx4*)(Cp + ((size_t)N_ + row) * D_ + lane * 4);
    float4 hv = *(const float4*)(Hf + row * D_ + lane * 4);
    attn[r][lane * 4 + 0] = f2bf(fmaf(bf2f(cA[0]) + bf2f(cB[0]) + rv.x, invL, hv.x));
    attn[r][lane * 4 + 1] = f2bf(fmaf(bf2f(cA[1]) + bf2f(cB[1]) + rv.y, invL, hv.y));
    attn[r][lane * 4 + 2] = f2bf(fmaf(bf2f(cA[2]) + bf2f(cB[2]) + rv.z, invL, hv.z));
    attn[r][lane * 4 + 3] = f2bf(fmaf(bf2f(cA[3]) + bf2f(cB[3]) + rv.w, invL, hv.w));
  }
  __syncthreads();

  f32x4 facc[8];
#pragma unroll
  for (int n = 0; n < 8; ++n) facc[n] = (f32x4){0.f, 0.f, 0.f, 0.f};
  const unsigned short* wwave = WtP + (size_t)chalf * 4096 + (size_t)lane * 8;
#pragma unroll
  for (int kf = 0; kf < 8; ++kf) {
    short8 af = *(const short8*)&attn[rtile * 16 + m][kf * 32 + q * 8];
#pragma unroll
    for (int n = 0; n < 8; ++n) {
      short8 bf = *(const short8*)(wwave + ((size_t)kf * 16 + n) * 512);
      facc[n] = __builtin_amdgcn_mfma_f32_16x16x32_bf16(af, bf, facc[n], 0, 0, 0);
    }
  }
#pragma unroll
  for (int n = 0; n < 8; ++n) {
    int col = chalf * 128 + n * 16 + m;
    float b = bt[col];
#pragma unroll
    for (int r = 0; r < 4; ++r) {
      size_t row = (size_t)i0 + rtile * 16 + q * 4 + r;
      out[row * O_ + col] = fmaxf(facc[n][r] + b, 0.0f);
    }
  }
}

// ---------------------------------------------------------------------------
extern "C" void kernel_launch(void* const* d_in, const int* in_sizes, int n_in,
                              void* d_out, int out_size, void* d_ws, size_t ws_size,
                              hipStream_t stream) {
  const float* Hf  = (const float*)d_in[0];  // [N,D]
  const float* Hc  = (const float*)d_in[1];  // [M,D]
  const float* adj = (const float*)d_in[2];  // [N,M]
  const float* wa  = (const float*)d_in[3];  // [2D]
  const float* ba  = (const float*)d_in[4];  // [1]
  const float* Wt  = (const float*)d_in[5];  // [O,D]
  const float* bt  = (const float*)d_in[6];  // [O]
  float* out = (float*)d_out;

  char* ws = (char*)d_ws;
  float* tv   = (float*)(ws + WS_T);
  float* uv   = (float*)(ws + WS_U);
  float* Rv   = (float*)(ws + WS_R);
  float* Lsum = (float*)(ws + WS_LSUM);
  unsigned short* WtP = (unsigned short*)(ws + WS_WTP);
  unsigned short* BP  = (unsigned short*)(ws + WS_BP);
  unsigned short* Cp  = (unsigned short*)(ws + WS_CP);
  unsigned short* AP  = (unsigned short*)(ws + WS_AP);

  hipMemsetAsync(Rv, 0, D_ * sizeof(float), stream);  // atomic target

  rowdot_exp_kernel<<<N_ / 4, 256, 0, stream>>>(Hf, wa, ba, tv);           // t = exp(sf+ba)
  rowdot_exp_kernel<<<M_ / 4, 256, 0, stream>>>(Hc, wa + D_, nullptr, uv); // u = exp(sc)
  hc_pack_kernel<<<256, 256, 0, stream>>>(Hc, BP, Rv);
  wt_pack_kernel<<<32, 256, 0, stream>>>(Wt, WtP);

  transform_kernel<<<N_ / 16, 256, 0, stream>>>(adj, tv, uv, AP, Lsum);
  main_kernel<<<1024, 256, 0, stream>>>(AP, BP, Cp);
  epilogue_kernel<<<N_ / 32, 256, 0, stream>>>(Cp, Lsum, Rv, Hf, WtP, bt, out);
}

// Round 7
// 490.270 us; speedup vs baseline: 1.4821x; 1.0483x over previous
//
#include <hip/hip_runtime.h>
#include <hip/hip_bf16.h>
#include <stdint.h>

// Problem constants (fixed by the reference)
#define N_ 16384
#define M_ 4096
#define D_ 256
#define O_ 256

// Workspace layout (bytes), total ~29 MB
#define WS_T    0          // float[N]        exp(sf+ba)       64 KB
#define WS_U    65536      // float[M]        exp(sc)          16 KB
#define WS_R    81920      // float[D]        colsum(Hc)        1 KB
#define WS_LSUM 98304      // float[N]        row denoms       64 KB
#define WS_WTP  163840     // ushort          Wt packed       128 KB
#define WS_BP   294912     // ushort          Hc packed         2 MB
#define WS_CP   2457600    // ushort[2*N*D]   partial C bf16   16 MB
#define WS_ABF  20971520   // uchar[1024*128*64] adj bits       8 MB

typedef float  f32x4  __attribute__((ext_vector_type(4)));
typedef short  short8 __attribute__((ext_vector_type(8)));
typedef unsigned short ushortx4 __attribute__((ext_vector_type(4)));

// fp32 -> bf16 (RNE). Inputs are finite so no NaN handling.
__device__ __forceinline__ unsigned short f2bf(float f) {
  uint32_t u = __float_as_uint(f);
  u += 0x7FFFu + ((u >> 16) & 1u);
  return (unsigned short)(u >> 16);
}
// packed pair fp32 -> bf16
__device__ __forceinline__ uint32_t cvtpk(float a, float b) {
  __hip_bfloat162 h = __float22bfloat162_rn(float2{a, b});
  uint32_t u;
  __builtin_memcpy(&u, &h, 4);
  return u;
}
__device__ __forceinline__ float bf2f(unsigned short v) {
  return __uint_as_float((uint32_t)v << 16);
}

// ---------------------------------------------------------------------------
// Prep 1: per-row dot with weight vector, then exp(dot + bias).
__global__ __launch_bounds__(256) void rowdot_exp_kernel(
    const float* __restrict__ X, const float* __restrict__ w,
    const float* __restrict__ bias, float* __restrict__ outv) {
  int wv = threadIdx.x >> 6, lane = threadIdx.x & 63;
  int row = blockIdx.x * 4 + wv;
  const float4* x4 = (const float4*)(X + (size_t)row * D_);
  const float4* w4 = (const float4*)w;
  float4 xa = x4[lane], wa4 = w4[lane];
  float s = xa.x * wa4.x + xa.y * wa4.y + xa.z * wa4.z + xa.w * wa4.w;
#pragma unroll
  for (int off = 32; off > 0; off >>= 1) s += __shfl_xor(s, off);
  if (lane == 0) outv[row] = expf(s + (bias ? bias[0] : 0.0f));
}

// ---------------------------------------------------------------------------
// Prep 2: Hc [M,D] fp32 -> BP fragment-major bf16 (standard k-order) + colsum.
// BP[((kg*16 + cg)*64 + lane)*8 + j] = bf16(Hc[kg*32+q*8+j][cg*16+m]), lane=q*16+m.
__global__ __launch_bounds__(256) void hc_pack_kernel(
    const float* __restrict__ Hc, unsigned short* __restrict__ BP,
    float* __restrict__ R) {
  __shared__ float tile[64][65];
  __shared__ float red[4][64];
  int bk = blockIdx.x >> 2;   // 64 tiles along M (k)
  int bc = blockIdx.x & 3;    // 4 tiles along D (col)
  int k0 = bk * 64, col0 = bc * 64;
  int t = threadIdx.x;
  int lane = t & 63, wv = t >> 6;
  int m = lane & 15, q = lane >> 4;
  float colsum = 0.0f;
#pragma unroll
  for (int i = 0; i < 16; ++i) {
    int e = t + 256 * i;
    int kk = e >> 6, cc = e & 63;
    float v = Hc[(size_t)(k0 + kk) * D_ + col0 + cc];
    tile[kk][cc] = v;
    colsum += v;
  }
  red[wv][t & 63] = colsum;
  __syncthreads();
  if (t < 64)
    atomicAdd(&R[col0 + t], red[0][t] + red[1][t] + red[2][t] + red[3][t]);
#pragma unroll
  for (int t8 = 0; t8 < 2; ++t8) {
    int tile_id = t8 * 4 + wv;
    int sub = tile_id >> 2, g = tile_id & 3;
    int kgg = bk * 2 + sub;
    int cgg = bc * 4 + g;
    short8 v8;
#pragma unroll
    for (int j = 0; j < 8; ++j)
      v8[j] = (short)f2bf(tile[sub * 32 + q * 8 + j][g * 16 + m]);
    *(short8*)(BP + ((size_t)(kgg * 16 + cgg) * 64 + lane) * 8) = v8;
  }
}

// ---------------------------------------------------------------------------
// Prep 3: Wt [O,D] fp32 -> WtP fragment-major bf16 (kg 0..7, cg 0..15).
__global__ __launch_bounds__(256) void wt_pack_kernel(
    const float* __restrict__ Wt, unsigned short* __restrict__ WtP) {
  int t = blockIdx.x * 256 + threadIdx.x;    // 0..8191
  int lane = t & 63, cg = (t >> 6) & 15, kg = t >> 10;
  int m = lane & 15, q = lane >> 4;
  const float* src = Wt + (size_t)(cg * 16 + m) * D_ + kg * 32 + q * 8;
  float4 w0 = *(const float4*)src, w1 = *(const float4*)(src + 4);
  short8 v8;
  v8[0] = (short)f2bf(w0.x); v8[1] = (short)f2bf(w0.y);
  v8[2] = (short)f2bf(w0.z); v8[3] = (short)f2bf(w0.w);
  v8[4] = (short)f2bf(w1.x); v8[5] = (short)f2bf(w1.y);
  v8[6] = (short)f2bf(w1.z); v8[7] = (short)f2bf(w1.w);
  *(short8*)(WtP + (size_t)t * 8) = v8;
}

// ---------------------------------------------------------------------------
// pack_bits: stream adj once; emit fragment-ordered bit bytes + exact row denoms.
//   ABF byte layout: ABF[((rt16*128 + ksg)*64) + lane] = bits j=0..7 where
//   bit j = (adj[rt16*16 + m][ksg*32 + q*8 + j] != 0), lane = q*16+m.
//   Lsum[i] = t_i * sum_j(adj_ij * u_j) - sum_j(adj_ij)   (fp32, in-block exact)
// Block = 32 rows (rt16 pair), 512 thr = 8 waves; wave w owns ks = w+8i (16 iters).
// Grid = N/32 = 512 -> 2 blocks/CU = 16 waves/CU.
__global__ __launch_bounds__(512, 2) void pack_bits_kernel(
    const float* __restrict__ adj, const float* __restrict__ tv,
    const float* __restrict__ uv, unsigned char* __restrict__ ABF,
    float* __restrict__ Lsum) {
  __shared__ float u_lds[M_];       // 16 KB
  __shared__ float redu[8][32];
  __shared__ float redc[8][32];
  int tid = threadIdx.x;
  int w = tid >> 6, lane = tid & 63;
  int q = lane >> 4, m = lane & 15;
  int b = blockIdx.x;
  int r0 = b * 32;

  for (int i = tid; i < M_; i += 512) u_lds[i] = uv[i];

  const float* a0 = adj + (size_t)(r0 + m) * M_ + q * 8;       // row m
  const float* a1 = a0 + (size_t)16 * M_;                      // row 16+m
  unsigned char* o0 = ABF + ((size_t)(2 * b) * 128) * 64 + lane;
  unsigned char* o1 = o0 + (size_t)128 * 64;
  float su0 = 0.f, sc0 = 0.f, su1 = 0.f, sc1 = 0.f;
  __syncthreads();  // u_lds ready

  // depth-1 register prefetch across iters
  int ks0 = w;
  float4 pa0 = *(const float4*)(a0 + ks0 * 32);
  float4 pa1 = *(const float4*)(a0 + ks0 * 32 + 4);
  float4 pb0 = *(const float4*)(a1 + ks0 * 32);
  float4 pb1 = *(const float4*)(a1 + ks0 * 32 + 4);

  for (int i = 0; i < 16; ++i) {
    int ks = w + 8 * i;
    int kn = (i + 1 < 16) ? ks + 8 : w;      // wrap: harmless reload
    float4 na0 = *(const float4*)(a0 + kn * 32);
    float4 na1 = *(const float4*)(a0 + kn * 32 + 4);
    float4 nb0 = *(const float4*)(a1 + kn * 32);
    float4 nb1 = *(const float4*)(a1 + kn * 32 + 4);

    float4 u0 = *(const float4*)&u_lds[ks * 32 + q * 8];
    float4 u1 = *(const float4*)&u_lds[ks * 32 + q * 8 + 4];
    float A[8] = {pa0.x, pa0.y, pa0.z, pa0.w, pa1.x, pa1.y, pa1.z, pa1.w};
    float B[8] = {pb0.x, pb0.y, pb0.z, pb0.w, pb1.x, pb1.y, pb1.z, pb1.w};
    float U[8] = {u0.x, u0.y, u0.z, u0.w, u1.x, u1.y, u1.z, u1.w};
    uint32_t bits0 = 0, bits1 = 0;
#pragma unroll
    for (int j = 0; j < 8; ++j) {
      bits0 |= (A[j] != 0.0f ? 1u : 0u) << j;
      bits1 |= (B[j] != 0.0f ? 1u : 0u) << j;
      su0 = fmaf(A[j], U[j], su0);  sc0 += A[j];
      su1 = fmaf(B[j], U[j], su1);  sc1 += B[j];
    }
    o0[(size_t)ks * 64] = (unsigned char)bits0;
    o1[(size_t)ks * 64] = (unsigned char)bits1;
    pa0 = na0; pa1 = na1; pb0 = nb0; pb1 = nb1;
  }

  // reduce over the 4 k-quads (lanes differ only in q)
  su0 += __shfl_xor(su0, 16); su0 += __shfl_xor(su0, 32);
  sc0 += __shfl_xor(sc0, 16); sc0 += __shfl_xor(sc0, 32);
  su1 += __shfl_xor(su1, 16); su1 += __shfl_xor(su1, 32);
  sc1 += __shfl_xor(sc1, 16); sc1 += __shfl_xor(sc1, 32);
  if (lane < 16) {
    redu[w][m] = su0;      redc[w][m] = sc0;
    redu[w][16 + m] = su1; redc[w][16 + m] = sc1;
  }
  __syncthreads();
  if (tid < 32) {
    float Su = 0.f, Sc = 0.f;
#pragma unroll
    for (int ww = 0; ww < 8; ++ww) { Su += redu[ww][tid]; Sc += redc[ww][tid]; }
    Lsum[r0 + tid] = tv[r0 + tid] * Su - Sc;
  }
}

// ---------------------------------------------------------------------------
// Build a bf16 MFMA A-fragment from 8 adj bits: slot j = bit_j ? (t*u_j - 1) : 0.
// Masking the packed bf16 pair with 0x0000 yields exact +0.0.
__device__ __forceinline__ short8 frag_bits(uint32_t bits, float t,
                                            float4 u0, float4 u1) {
  float c[8];
  c[0] = fmaf(t, u0.x, -1.0f); c[1] = fmaf(t, u0.y, -1.0f);
  c[2] = fmaf(t, u0.z, -1.0f); c[3] = fmaf(t, u0.w, -1.0f);
  c[4] = fmaf(t, u1.x, -1.0f); c[5] = fmaf(t, u1.y, -1.0f);
  c[6] = fmaf(t, u1.z, -1.0f); c[7] = fmaf(t, u1.w, -1.0f);
  union { short8 s; uint32_t u[4]; } r;
#pragma unroll
  for (int p = 0; p < 4; ++p) {
    uint32_t mlo = 0u - ((bits >> (2 * p)) & 1u);      // 0 or ~0
    uint32_t mhi = 0u - ((bits >> (2 * p + 1)) & 1u);
    r.u[p] = cvtpk(c[2 * p], c[2 * p + 1]) &
             ((mlo & 0x0000FFFFu) | (mhi & 0xFFFF0000u));
  }
  return r.s;
}

// ---------------------------------------------------------------------------
// Main GEMM (barrier-free K loop): C_partial = A' @ Hc with A' rebuilt from
// bits in registers. B fragments from prepacked BP (L2-resident). Block =
// 32 rows x 256 cols (4 waves split cols), split-K=2 across blocks.
// Grid = 1024 x 256 thr -> 4 blocks/CU = 16 waves/CU. Depth-1 X/Y register
// prefetch on bits+B; u table in LDS (8 KB, kh half).
__global__ __launch_bounds__(256, 4) void main_kernel(
    const unsigned char* __restrict__ ABF, const unsigned short* __restrict__ BP,
    const float* __restrict__ tv, const float* __restrict__ uv,
    unsigned short* __restrict__ Cp) {
  __shared__ float u_lds[2048];
  int tid = threadIdx.x;
  int w = tid >> 6, lane = tid & 63;
  int q = lane >> 4, m = lane & 15;
  int bid = blockIdx.x;
  int kh = bid & 1, rb = bid >> 1;
  int c0 = w * 64;

  for (int i = tid; i < 2048; i += 256) u_lds[i] = uv[kh * 2048 + i];

  float t0 = tv[rb * 32 + m], t1 = tv[rb * 32 + 16 + m];
  const unsigned char* g0 =
      ABF + ((size_t)(2 * rb) * 128 + kh * 64) * 64 + lane;
  const unsigned char* g1 = g0 + (size_t)128 * 64;
  const unsigned short* bb =
      BP + ((size_t)(kh * 64) * 16 + w * 4) * 512 + (size_t)lane * 8;

  f32x4 acc[2][4];
#pragma unroll
  for (int s = 0; s < 2; ++s)
#pragma unroll
    for (int n = 0; n < 4; ++n) acc[s][n] = (f32x4){0.f, 0.f, 0.f, 0.f};

  __syncthreads();  // u_lds ready (only barrier)

  // X = even ksteps, Y = odd ksteps
  uint32_t xb0 = g0[0], xb1 = g1[0];
  uint32_t yb0 = g0[64], yb1 = g1[64];
  short8 BX[4], BY[4];
#pragma unroll
  for (int n = 0; n < 4; ++n) BX[n] = *(const short8*)(bb + n * 512);
#pragma unroll
  for (int n = 0; n < 4; ++n) BY[n] = *(const short8*)(bb + 8192 + n * 512);

  for (int kk = 0; kk < 64; kk += 2) {
    // consume kstep kk (X), prefetch kk+2 into X
    {
      int k2 = (kk + 2) & 63;      // wrap: harmless reload
      uint32_t nb0 = g0[(size_t)k2 * 64], nb1 = g1[(size_t)k2 * 64];
      short8 nB[4];
#pragma unroll
      for (int n = 0; n < 4; ++n)
        nB[n] = *(const short8*)(bb + (size_t)k2 * 8192 + n * 512);
      float4 u0 = *(const float4*)&u_lds[kk * 32 + q * 8];
      float4 u1 = *(const float4*)&u_lds[kk * 32 + q * 8 + 4];
      short8 af0 = frag_bits(xb0, t0, u0, u1);
      short8 af1 = frag_bits(xb1, t1, u0, u1);
#pragma unroll
      for (int n = 0; n < 4; ++n) {
        acc[0][n] = __builtin_amdgcn_mfma_f32_16x16x32_bf16(af0, BX[n], acc[0][n], 0, 0, 0);
        acc[1][n] = __builtin_amdgcn_mfma_f32_16x16x32_bf16(af1, BX[n], acc[1][n], 0, 0, 0);
      }
      xb0 = nb0; xb1 = nb1;
#pragma unroll
      for (int n = 0; n < 4; ++n) BX[n] = nB[n];
    }
    // consume kstep kk+1 (Y), prefetch kk+3 into Y
    {
      int k3 = (kk + 3) & 63;
      uint32_t nb0 = g0[(size_t)k3 * 64], nb1 = g1[(size_t)k3 * 64];
      short8 nB[4];
#pragma unroll
      for (int n = 0; n < 4; ++n)
        nB[n] = *(const short8*)(bb + (size_t)k3 * 8192 + n * 512);
      float4 u0 = *(const float4*)&u_lds[(kk + 1) * 32 + q * 8];
      float4 u1 = *(const float4*)&u_lds[(kk + 1) * 32 + q * 8 + 4];
      short8 af0 = frag_bits(yb0, t0, u0, u1);
      short8 af1 = frag_bits(yb1, t1, u0, u1);
#pragma unroll
      for (int n = 0; n < 4; ++n) {
        acc[0][n] = __builtin_amdgcn_mfma_f32_16x16x32_bf16(af0, BY[n], acc[0][n], 0, 0, 0);
        acc[1][n] = __builtin_amdgcn_mfma_f32_16x16x32_bf16(af1, BY[n], acc[1][n], 0, 0, 0);
      }
      yb0 = nb0; yb1 = nb1;
#pragma unroll
      for (int n = 0; n < 4; ++n) BY[n] = nB[n];
    }
  }

  // partial C -> bf16 plain stores
#pragma unroll
  for (int s = 0; s < 2; ++s)
#pragma unroll
    for (int n = 0; n < 4; ++n) {
      int col = c0 + n * 16 + m;
#pragma unroll
      for (int r = 0; r < 4; ++r) {
        size_t row = (size_t)rb * 32 + s * 16 + q * 4 + r;  // C/D: row=(lane>>4)*4+reg
        Cp[((size_t)kh * N_ + row) * D_ + col] = f2bf(acc[s][n][r]);
      }
    }
}

// ---------------------------------------------------------------------------
// Epilogue: attn = (Cp0+Cp1 + R)/(Lsum + M) + Hf -> LDS bf16 -> relu(attn@Wt^T+bt)
__global__ __launch_bounds__(256, 4) void epilogue_kernel(
    const unsigned short* __restrict__ Cp, const float* __restrict__ Lsum,
    const float* __restrict__ Rv, const float* __restrict__ Hf,
    const unsigned short* __restrict__ WtP, const float* __restrict__ bt,
    float* __restrict__ out) {
  __shared__ alignas(16) unsigned short attn[32][264];  // +8 pad
  int tid = threadIdx.x;
  int w = tid >> 6, lane = tid & 63;
  int rtile = w & 1, chalf = w >> 1;
  int q = lane >> 4, m = lane & 15;
  int i0 = blockIdx.x * 32;

  float4 rv = *(const float4*)(Rv + lane * 4);
#pragma unroll
  for (int rr = 0; rr < 8; ++rr) {
    int r = w * 8 + rr;                       // wave w owns rows w*8..w*8+7
    size_t row = (size_t)i0 + r;
    float invL = 1.0f / (Lsum[row] + (float)M_);
    ushortx4 cA = *(const ushortx4*)(Cp + row * D_ + lane * 4);
    ushortx4 cB = *(const ushortx4*)(Cp + ((size_t)N_ + row) * D_ + lane * 4);
    float4 hv = *(const float4*)(Hf + row * D_ + lane * 4);
    attn[r][lane * 4 + 0] = f2bf(fmaf(bf2f(cA[0]) + bf2f(cB[0]) + rv.x, invL, hv.x));
    attn[r][lane * 4 + 1] = f2bf(fmaf(bf2f(cA[1]) + bf2f(cB[1]) + rv.y, invL, hv.y));
    attn[r][lane * 4 + 2] = f2bf(fmaf(bf2f(cA[2]) + bf2f(cB[2]) + rv.z, invL, hv.z));
    attn[r][lane * 4 + 3] = f2bf(fmaf(bf2f(cA[3]) + bf2f(cB[3]) + rv.w, invL, hv.w));
  }
  __syncthreads();

  f32x4 facc[8];
#pragma unroll
  for (int n = 0; n < 8; ++n) facc[n] = (f32x4){0.f, 0.f, 0.f, 0.f};
  const unsigned short* wwave = WtP + (size_t)chalf * 4096 + (size_t)lane * 8;
#pragma unroll
  for (int kf = 0; kf < 8; ++kf) {
    short8 af = *(const short8*)&attn[rtile * 16 + m][kf * 32 + q * 8];
#pragma unroll
    for (int n = 0; n < 8; ++n) {
      short8 bf = *(const short8*)(wwave + ((size_t)kf * 16 + n) * 512);
      facc[n] = __builtin_amdgcn_mfma_f32_16x16x32_bf16(af, bf, facc[n], 0, 0, 0);
    }
  }
#pragma unroll
  for (int n = 0; n < 8; ++n) {
    int col = chalf * 128 + n * 16 + m;
    float b = bt[col];
#pragma unroll
    for (int r = 0; r < 4; ++r) {
      size_t row = (size_t)i0 + rtile * 16 + q * 4 + r;
      out[row * O_ + col] = fmaxf(facc[n][r] + b, 0.0f);
    }
  }
}

// ---------------------------------------------------------------------------
extern "C" void kernel_launch(void* const* d_in, const int* in_sizes, int n_in,
                              void* d_out, int out_size, void* d_ws, size_t ws_size,
                              hipStream_t stream) {
  const float* Hf  = (const float*)d_in[0];  // [N,D]
  const float* Hc  = (const float*)d_in[1];  // [M,D]
  const float* adj = (const float*)d_in[2];  // [N,M]
  const float* wa  = (const float*)d_in[3];  // [2D]
  const float* ba  = (const float*)d_in[4];  // [1]
  const float* Wt  = (const float*)d_in[5];  // [O,D]
  const float* bt  = (const float*)d_in[6];  // [O]
  float* out = (float*)d_out;

  char* ws = (char*)d_ws;
  float* tv   = (float*)(ws + WS_T);
  float* uv   = (float*)(ws + WS_U);
  float* Rv   = (float*)(ws + WS_R);
  float* Lsum = (float*)(ws + WS_LSUM);
  unsigned short* WtP = (unsigned short*)(ws + WS_WTP);
  unsigned short* BP  = (unsigned short*)(ws + WS_BP);
  unsigned short* Cp  = (unsigned short*)(ws + WS_CP);
  unsigned char*  ABF = (unsigned char*)(ws + WS_ABF);

  hipMemsetAsync(Rv, 0, D_ * sizeof(float), stream);  // atomic target

  rowdot_exp_kernel<<<N_ / 4, 256, 0, stream>>>(Hf, wa, ba, tv);           // t = exp(sf+ba)
  rowdot_exp_kernel<<<M_ / 4, 256, 0, stream>>>(Hc, wa + D_, nullptr, uv); // u = exp(sc)
  hc_pack_kernel<<<256, 256, 0, stream>>>(Hc, BP, Rv);
  wt_pack_kernel<<<32, 256, 0, stream>>>(Wt, WtP);

  pack_bits_kernel<<<N_ / 32, 512, 0, stream>>>(adj, tv, uv, ABF, Lsum);
  main_kernel<<<1024, 256, 0, stream>>>(ABF, BP, tv, uv, Cp);
  epilogue_kernel<<<N_ / 32, 256, 0, stream>>>(Cp, Lsum, Rv, Hf, WtP, bt, out);
}